// Round 4
// baseline (277.181 us; speedup 1.0000x reference)
//
#include <hip/hip_runtime.h>
#include <hip/hip_cooperative_groups.h>
#include <cstdint>
#include <cstddef>

namespace cg = cooperative_groups;

#define NB 20000
#define NT 1000
#define P_PAIRS 50000
#define MARGIN 2.0f
#define RANK_W 0.3f
#define NEG_SENT -1e9f

#define BLOCK_THREADS 256
#define MAX_COOP_BLOCKS 512

// ---------------- workspace layout (bytes) ----------------
// [0,        2560000)  label bitmask: uint32 [NB][32]   (= 160000 uint4)
// [2560000,  2960000)  float top5[NB][5]
// [2960000,  3040000)  int   numneg[NB]
// [3040000,  3040004)  float sq_total
// [3040004,  3040008)  float rsum
// [3040008,  3040012)  uint  nrp
// [3040016,  3120016)  float sq_partials[NB]   (fallback path only)

// ============================================================
// Fused cooperative kernel (runtime grid size via gridDim.x)
// ============================================================
__global__ __launch_bounds__(BLOCK_THREADS, 4)
void fused_loss_kernel(const float* __restrict__ scores,
                       const int* __restrict__ pb,
                       const int* __restrict__ pt,
                       unsigned int* __restrict__ mask,
                       float* __restrict__ top5,
                       int* __restrict__ numneg,
                       float* __restrict__ sq_total,
                       float* __restrict__ rsum,
                       unsigned int* __restrict__ nrp,
                       float* __restrict__ out) {
    cg::grid_group grid = cg::this_grid();
    const int nthreads = gridDim.x * BLOCK_THREADS;
    const int tid = blockIdx.x * BLOCK_THREADS + threadIdx.x;
    const int lane = threadIdx.x & 63;
    const int wib  = threadIdx.x >> 6;          // wave in block (0..3)

    // ---- Phase A: zero mask + accumulators ----
    uint4* m4 = reinterpret_cast<uint4*>(mask);
    for (int i = tid; i < 160000; i += nthreads) m4[i] = make_uint4(0u, 0u, 0u, 0u);
    if (tid == 0) { *sq_total = 0.0f; *rsum = 0.0f; *nrp = 0u; }
    grid.sync();

    // ---- Phase B: scatter positive labels ----
    for (int p = tid; p < P_PAIRS; p += nthreads) {
        int b = pb[p];
        int t = pt[p];
        atomicOr(&mask[b * 32 + (t >> 5)], 1u << (t & 31));
    }
    grid.sync();

    // ---- Phase C: per-row sq-loss, top-5 negatives, numneg ----
    const int gwave  = blockIdx.x * 4 + wib;
    const int nwaves = gridDim.x * 4;
    float sq_acc = 0.0f;

    for (int row = gwave; row < NB; row += nwaves) {
        const float4* rowp = reinterpret_cast<const float4*>(scores + (size_t)row * NT);
        const unsigned int* mrow = mask + row * 32;

        // NT/4 = 250 float4 per row: lane, +64, +128, (+192 if < 250)
        const bool has3 = (lane + 192) < 250;
        float4 v0 = rowp[lane];
        float4 v1 = rowp[lane + 64];
        float4 v2 = rowp[lane + 128];
        float4 v3 = has3 ? rowp[lane + 192] : make_float4(0.f, 0.f, 0.f, 0.f);
        // element index e_g = lane*4 + 256*g; shift (e & 31) identical for all g
        const int sh = (lane * 4) & 31;
        unsigned int b0 = (mrow[(lane * 4) >> 5]         >> sh) & 0xFu;
        unsigned int b1 = (mrow[((lane + 64) * 4) >> 5]  >> sh) & 0xFu;
        unsigned int b2 = (mrow[((lane + 128) * 4) >> 5] >> sh) & 0xFu;
        unsigned int b3 = has3 ? ((mrow[((lane + 192) * 4) >> 5] >> sh) & 0xFu) : 0xFu;

        float t0 = NEG_SENT, t1 = NEG_SENT, t2 = NEG_SENT, t3 = NEG_SENT, t4 = NEG_SENT;
        float sq = 0.0f;
        int pcount = 0;

        float4       vv[4] = {v0, v1, v2, v3};
        unsigned int bb[4] = {b0, b1, b2, b3};
        #pragma unroll
        for (int g = 0; g < 4; ++g) {
            if (g == 3 && !has3) break;
            float e4[4] = {vv[g].x, vv[g].y, vv[g].z, vv[g].w};
            #pragma unroll
            for (int j = 0; j < 4; ++j) {
                float x = e4[j];
                float s = 1.0f / (1.0f + __expf(-x));
                int lab = (bb[g] >> j) & 1;
                float d = (float)lab - s;
                sq += d * d;
                if (lab) {
                    pcount++;
                } else if (x > t4) {
                    if (x > t0)      { t4 = t3; t3 = t2; t2 = t1; t1 = t0; t0 = x; }
                    else if (x > t1) { t4 = t3; t3 = t2; t2 = t1; t1 = x; }
                    else if (x > t2) { t4 = t3; t3 = t2; t2 = x; }
                    else if (x > t3) { t4 = t3; t3 = x; }
                    else             { t4 = x; }
                }
            }
        }

        #pragma unroll
        for (int off = 32; off >= 1; off >>= 1) {
            sq     += __shfl_xor(sq, off);
            pcount += __shfl_xor(pcount, off);
        }

        // wave-merge top-5: 5 rounds of argmax + pop
        float t[5] = {t0, t1, t2, t3, t4};
        float r[5];
        #pragma unroll
        for (int k = 0; k < 5; ++k) {
            float v = t[0];
            float m = v;
            #pragma unroll
            for (int off = 32; off >= 1; off >>= 1) m = fmaxf(m, __shfl_xor(m, off));
            unsigned long long ball = __ballot(v == m);
            int owner = __ffsll(ball) - 1;
            if (lane == owner) { t[0] = t[1]; t[1] = t[2]; t[2] = t[3]; t[3] = t[4]; t[4] = NEG_SENT; }
            r[k] = m;
        }

        if (lane == 0) {
            sq_acc += sq;
            #pragma unroll
            for (int k = 0; k < 5; ++k) top5[row * 5 + k] = r[k];
            numneg[row] = NT - pcount;
        }
    }

    __shared__ float ssq[4];
    if (lane == 0) ssq[wib] = sq_acc;
    __syncthreads();
    if (threadIdx.x == 0) atomicAdd(sq_total, ssq[0] + ssq[1] + ssq[2] + ssq[3]);
    grid.sync();

    // ---- Phase D: per-pair ranking contributions ----
    float c = 0.0f;
    unsigned int valid = 0;
    for (int p = tid; p < P_PAIRS; p += nthreads) {
        int b = pb[p];
        int t = pt[p];
        float pos = scores[(size_t)b * NT + t];
        #pragma unroll
        for (int k = 0; k < 5; ++k) {
            float tn = top5[b * 5 + k];
            float contrib = MARGIN - (pos - tn);
            c += contrib > 0.0f ? contrib : 0.0f;
        }
        int nn = numneg[b];
        valid += (unsigned int)(nn < 5 ? nn : 5);
    }
    #pragma unroll
    for (int off = 32; off >= 1; off >>= 1) {
        c     += __shfl_xor(c, off);
        valid += __shfl_xor(valid, off);
    }
    __shared__ float sc[4];
    __shared__ unsigned int sv[4];
    if (lane == 0) { sc[wib] = c; sv[wib] = valid; }
    __syncthreads();
    if (threadIdx.x == 0) {
        float cb = sc[0] + sc[1] + sc[2] + sc[3];
        unsigned int vb = sv[0] + sv[1] + sv[2] + sv[3];
        if (cb != 0.0f) atomicAdd(rsum, cb);
        if (vb != 0u)   atomicAdd(nrp, vb);
    }
    grid.sync();

    // ---- Phase E: finalize ----
    if (tid == 0) {
        float loss = 0.5f * (*sq_total) / 2.0e7f;   // NB*NT = 2e7
        unsigned int n = *nrp;
        if (n > 0) loss += RANK_W * (*rsum) / (float)n;
        out[0] = loss;
    }
}

// ============================================================
// Fallback pipeline (proven-correct R2 structure)
// ============================================================
__global__ void zero_ws_kernel(uint4* __restrict__ m4, float* __restrict__ sq_total,
                               float* __restrict__ rsum, unsigned int* __restrict__ nrp) {
    int i = blockIdx.x * blockDim.x + threadIdx.x;
    if (i < 160000) m4[i] = make_uint4(0u, 0u, 0u, 0u);
    if (i == 0) { *sq_total = 0.0f; *rsum = 0.0f; *nrp = 0u; }
}

__global__ void scatter_labels_kernel(const int* __restrict__ pb,
                                      const int* __restrict__ pt,
                                      unsigned int* __restrict__ mask) {
    int p = blockIdx.x * blockDim.x + threadIdx.x;
    if (p >= P_PAIRS) return;
    atomicOr(&mask[pb[p] * 32 + (pt[p] >> 5)], 1u << (pt[p] & 31));
}

__global__ void row_kernel(const float* __restrict__ scores,
                           const unsigned int* __restrict__ mask,
                           float* __restrict__ sq_partials,
                           float* __restrict__ top5,
                           int* __restrict__ numneg) {
    const int wave = threadIdx.x >> 6;
    const int lane = threadIdx.x & 63;
    const int row  = blockIdx.x * 4 + wave;
    if (row >= NB) return;

    const float4* rowp = reinterpret_cast<const float4*>(scores + (size_t)row * NT);
    const unsigned int* mrow = mask + row * 32;

    float t0 = NEG_SENT, t1 = NEG_SENT, t2 = NEG_SENT, t3 = NEG_SENT, t4 = NEG_SENT;
    float sq = 0.0f;
    int pcount = 0;

    for (int i = lane; i < NT / 4; i += 64) {
        float4 v = rowp[i];
        int e = i * 4;
        unsigned int bits = (mrow[e >> 5] >> (e & 31)) & 0xFu;
        float vv[4] = {v.x, v.y, v.z, v.w};
        #pragma unroll
        for (int j = 0; j < 4; ++j) {
            float x = vv[j];
            float s = 1.0f / (1.0f + __expf(-x));
            int lab = (bits >> j) & 1;
            float d = (float)lab - s;
            sq += d * d;
            if (lab) {
                pcount++;
            } else if (x > t4) {
                if (x > t0)      { t4 = t3; t3 = t2; t2 = t1; t1 = t0; t0 = x; }
                else if (x > t1) { t4 = t3; t3 = t2; t2 = t1; t1 = x; }
                else if (x > t2) { t4 = t3; t3 = t2; t2 = x; }
                else if (x > t3) { t4 = t3; t3 = x; }
                else             { t4 = x; }
            }
        }
    }
    #pragma unroll
    for (int off = 32; off >= 1; off >>= 1) {
        sq     += __shfl_xor(sq, off);
        pcount += __shfl_xor(pcount, off);
    }
    float t[5] = {t0, t1, t2, t3, t4};
    float r[5];
    #pragma unroll
    for (int k = 0; k < 5; ++k) {
        float v = t[0];
        float m = v;
        #pragma unroll
        for (int off = 32; off >= 1; off >>= 1) m = fmaxf(m, __shfl_xor(m, off));
        unsigned long long ball = __ballot(v == m);
        int owner = __ffsll(ball) - 1;
        if (lane == owner) { t[0] = t[1]; t[1] = t[2]; t[2] = t[3]; t[3] = t[4]; t[4] = NEG_SENT; }
        r[k] = m;
    }
    if (lane == 0) {
        sq_partials[row] = sq;
        #pragma unroll
        for (int k = 0; k < 5; ++k) top5[row * 5 + k] = r[k];
        numneg[row] = NT - pcount;
    }
}

__global__ void pair_kernel(const float* __restrict__ scores,
                            const int* __restrict__ pb,
                            const int* __restrict__ pt,
                            const float* __restrict__ top5,
                            const int* __restrict__ numneg,
                            float* __restrict__ rsum,
                            unsigned int* __restrict__ nrp) {
    int p = blockIdx.x * blockDim.x + threadIdx.x;
    float c = 0.0f;
    unsigned int valid = 0;
    if (p < P_PAIRS) {
        int b = pb[p];
        float pos = scores[(size_t)b * NT + pt[p]];
        #pragma unroll
        for (int k = 0; k < 5; ++k) {
            float contrib = MARGIN - (pos - top5[b * 5 + k]);
            c += contrib > 0.0f ? contrib : 0.0f;
        }
        int nn = numneg[b];
        valid = (unsigned int)(nn < 5 ? nn : 5);
    }
    #pragma unroll
    for (int off = 32; off >= 1; off >>= 1) {
        c     += __shfl_xor(c, off);
        valid += __shfl_xor(valid, off);
    }
    if ((threadIdx.x & 63) == 0) {
        atomicAdd(rsum, c);
        atomicAdd(nrp, valid);
    }
}

__global__ void finalize_kernel(const float* __restrict__ sq_partials,
                                const float* __restrict__ rsum,
                                const unsigned int* __restrict__ nrp,
                                float* __restrict__ out) {
    float s = 0.0f;
    for (int i = threadIdx.x; i < NB; i += blockDim.x) s += sq_partials[i];
    #pragma unroll
    for (int off = 32; off >= 1; off >>= 1) s += __shfl_xor(s, off);
    __shared__ float smem[8];
    int wave = threadIdx.x >> 6;
    int lane = threadIdx.x & 63;
    if (lane == 0) smem[wave] = s;
    __syncthreads();
    if (threadIdx.x == 0) {
        float tot = 0.0f;
        for (int w = 0; w < (int)(blockDim.x >> 6); ++w) tot += smem[w];
        float loss = 0.5f * tot / 2.0e7f;
        unsigned int n = *nrp;
        if (n > 0) loss += RANK_W * (*rsum) / (float)n;
        out[0] = loss;
    }
}

extern "C" void kernel_launch(void* const* d_in, const int* in_sizes, int n_in,
                              void* d_out, int out_size, void* d_ws, size_t ws_size,
                              hipStream_t stream) {
    const float* scores = (const float*)d_in[0];
    const int*   pb     = (const int*)d_in[1];
    const int*   pt     = (const int*)d_in[2];
    float*       out    = (float*)d_out;

    char* ws = (char*)d_ws;
    unsigned int* mask        = (unsigned int*)ws;
    float*        top5        = (float*)(ws + 2560000);
    int*          numneg      = (int*)(ws + 2960000);
    float*        sq_total    = (float*)(ws + 3040000);
    float*        rsum        = (float*)(ws + 3040004);
    unsigned int* nrp         = (unsigned int*)(ws + 3040008);
    float*        sq_partials = (float*)(ws + 3040016);

    // Try the fused cooperative path with a runtime-validated grid size.
    int occ = 0;
    hipError_t oerr = hipOccupancyMaxActiveBlocksPerMultiprocessor(
        &occ, (const void*)fused_loss_kernel, BLOCK_THREADS, 0);
    bool coop_ok = false;
    if (oerr == hipSuccess && occ >= 1) {
        int nblocks = occ * 256;                    // 256 CUs on MI355X
        if (nblocks > MAX_COOP_BLOCKS) nblocks = MAX_COOP_BLOCKS;
        void* args[] = {(void*)&scores, (void*)&pb, (void*)&pt, (void*)&mask,
                        (void*)&top5, (void*)&numneg, (void*)&sq_total,
                        (void*)&rsum, (void*)&nrp, (void*)&out};
        hipError_t lerr = hipLaunchCooperativeKernel((const void*)fused_loss_kernel,
                                                     dim3(nblocks), dim3(BLOCK_THREADS),
                                                     args, 0, stream);
        coop_ok = (lerr == hipSuccess);
    }

    if (!coop_ok) {
        // Proven fallback pipeline (R2: 84 us)
        zero_ws_kernel<<<(160000 + 255) / 256, 256, 0, stream>>>((uint4*)ws, sq_total, rsum, nrp);
        scatter_labels_kernel<<<(P_PAIRS + 255) / 256, 256, 0, stream>>>(pb, pt, mask);
        row_kernel<<<NB / 4, 256, 0, stream>>>(scores, mask, sq_partials, top5, numneg);
        pair_kernel<<<(P_PAIRS + 255) / 256, 256, 0, stream>>>(scores, pb, pt, top5, numneg, rsum, nrp);
        finalize_kernel<<<1, 256, 0, stream>>>(sq_partials, rsum, nrp, out);
    }
}

// Round 5
// 51.621 us; speedup vs baseline: 5.3695x; 5.3695x over previous
//
#include <hip/hip_runtime.h>
#include <cstdint>
#include <cstddef>

#define NB 20000
#define NT 1000
#define P_PAIRS 50000
#define MARGIN 2.0f
#define RANK_W 0.3f
#define NEG_SENT -1e9f

// ---------------- workspace layout (bytes) ----------------
// [0,        2560000)  label bitmask: uint32 [NB][32]
// [2560000,  2560004)  float sq_total
// [2560004,  2560008)  float rsum
// [2560008,  2560012)  uint  nrp
// [2560012,  2560016)  uint  ticket
// zero range [0, 2560016) = 160001 uint4
// [2560016,  2960016)  float top5[NB][5]
// [2960016,  3040016)  int   numneg[NB]

#define ZERO_U4 160001

__global__ void zero_ws_kernel(uint4* __restrict__ ws) {
    int i = blockIdx.x * blockDim.x + threadIdx.x;
    if (i < ZERO_U4) ws[i] = make_uint4(0u, 0u, 0u, 0u);
}

__global__ void scatter_labels_kernel(const int* __restrict__ pb,
                                      const int* __restrict__ pt,
                                      unsigned int* __restrict__ mask) {
    int p = blockIdx.x * blockDim.x + threadIdx.x;
    if (p >= P_PAIRS) return;
    int b = pb[p];
    int t = pt[p];
    atomicOr(&mask[b * 32 + (t >> 5)], 1u << (t & 31));
}

// branchless sorted-desc insert of x into (t0>=t1>=t2>=t3>=t4)
#define INSERT5(x)                                        \
    {                                                     \
        float _x = (x);                                   \
        float n0 = fmaxf(t0, _x), s0 = fminf(t0, _x);     \
        float n1 = fmaxf(t1, s0), s1 = fminf(t1, s0);     \
        float n2 = fmaxf(t2, s1), s2 = fminf(t2, s1);     \
        float n3 = fmaxf(t3, s2), s3 = fminf(t3, s2);     \
        float n4 = fmaxf(t4, s3);                         \
        t0 = n0; t1 = n1; t2 = n2; t3 = n3; t4 = n4;      \
    }

// Row kernel v2: 16 lanes per row, 4 rows per wave, 16 rows per 256-block.
// grid = NB/16 = 1250 blocks.
__global__ __launch_bounds__(256)
void row_kernel(const float* __restrict__ scores,
                const unsigned int* __restrict__ mask,
                float* __restrict__ sq_total,
                float* __restrict__ top5,
                int* __restrict__ numneg) {
    const int lane = threadIdx.x & 63;
    const int wib  = threadIdx.x >> 6;      // wave in block 0..3
    const int grp  = lane >> 4;             // group in wave  0..3
    const int gl   = lane & 15;             // lane in group  0..15
    const int row  = blockIdx.x * 16 + wib * 4 + grp;

    const float4* rowp = reinterpret_cast<const float4*>(scores + (size_t)row * NT);
    const unsigned int* mrow = mask + row * 32;

    float t0 = NEG_SENT, t1 = NEG_SENT, t2 = NEG_SENT, t3 = NEG_SENT, t4 = NEG_SENT;
    float sq = 0.0f;
    int pcount = 0;

    // NT/4 = 250 float4; lanes gl<10 do 16 iters, others 15.
    for (int i = gl; i < 250; i += 16) {
        float4 v = rowp[i];
        unsigned int bits = (mrow[i >> 3] >> ((i & 7) * 4)) & 0xFu;
        float xs[4] = {v.x, v.y, v.z, v.w};
        #pragma unroll
        for (int j = 0; j < 4; ++j) {
            float x = xs[j];
            int lab = (bits >> j) & 1;
            float s = __builtin_amdgcn_rcpf(1.0f + __expf(-x));
            float d = (float)lab - s;
            sq = fmaf(d, d, sq);
            pcount += lab;
            float xx = lab ? NEG_SENT : x;
            INSERT5(xx);
        }
    }

    // 4 xor-rounds within each 16-lane group: merge sorted-5 + reduce sq/pcount
    #pragma unroll
    for (int off = 8; off >= 1; off >>= 1) {
        float b0 = __shfl_xor(t0, off, 16);
        float b1 = __shfl_xor(t1, off, 16);
        float b2 = __shfl_xor(t2, off, 16);
        float b3 = __shfl_xor(t3, off, 16);
        float b4 = __shfl_xor(t4, off, 16);
        sq     += __shfl_xor(sq, off, 16);
        pcount += __shfl_xor(pcount, off, 16);

        // c_i = max over {a_i, b_i, min(a_{j}, b_{k}) : j+k = i-1}
        float m1  = fminf(t0, b0);
        float m2a = fminf(t1, b0), m2b = fminf(t0, b1);
        float m3a = fminf(t2, b0), m3b = fminf(t1, b1), m3c = fminf(t0, b2);
        float m4a = fminf(t3, b0), m4b = fminf(t2, b1), m4c = fminf(t1, b2), m4d = fminf(t0, b3);
        float c0 = fmaxf(t0, b0);
        float c1 = fmaxf(fmaxf(t1, b1), m1);
        float c2 = fmaxf(fmaxf(t2, b2), fmaxf(m2a, m2b));
        float c3 = fmaxf(fmaxf(t3, b3), fmaxf(fmaxf(m3a, m3b), m3c));
        float c4 = fmaxf(fmaxf(t4, b4), fmaxf(fmaxf(m4a, m4b), fmaxf(m4c, m4d)));
        t0 = c0; t1 = c1; t2 = c2; t3 = c3; t4 = c4;
    }

    // group leader writes per-row results
    if (gl == 0) {
        float* tp = top5 + (size_t)row * 5;
        tp[0] = t0; tp[1] = t1; tp[2] = t2; tp[3] = t3; tp[4] = t4;
        numneg[row] = NT - pcount;
    }

    // block-reduce sq (16 group leaders) -> 1 atomic per block
    __shared__ float bsq[16];
    if (gl == 0) bsq[(threadIdx.x >> 4)] = sq;
    __syncthreads();
    if (threadIdx.x == 0) {
        float s = 0.0f;
        #pragma unroll
        for (int k = 0; k < 16; ++k) s += bsq[k];
        atomicAdd(sq_total, s);
    }
}

// pair contributions + last-block finalize (ticket pattern, no co-residency needed)
__global__ __launch_bounds__(256)
void pair_finalize_kernel(const float* __restrict__ scores,
                          const int* __restrict__ pb,
                          const int* __restrict__ pt,
                          const float* __restrict__ top5,
                          const int* __restrict__ numneg,
                          float* __restrict__ sq_total,
                          float* __restrict__ rsum,
                          unsigned int* __restrict__ nrp,
                          unsigned int* __restrict__ ticket,
                          float* __restrict__ out) {
    int p = blockIdx.x * blockDim.x + threadIdx.x;
    float c = 0.0f;
    unsigned int valid = 0;
    if (p < P_PAIRS) {
        int b = pb[p];
        int t = pt[p];
        float pos = scores[(size_t)b * NT + t];
        const float* tp = top5 + (size_t)b * 5;
        #pragma unroll
        for (int k = 0; k < 5; ++k) {
            float contrib = MARGIN - (pos - tp[k]);
            c += contrib > 0.0f ? contrib : 0.0f;
        }
        int nn = numneg[b];
        valid = (unsigned int)(nn < 5 ? nn : 5);
    }
    #pragma unroll
    for (int off = 32; off >= 1; off >>= 1) {
        c     += __shfl_xor(c, off);
        valid += __shfl_xor(valid, off);
    }
    __shared__ float sc[4];
    __shared__ unsigned int sv[4];
    const int wib = threadIdx.x >> 6;
    if ((threadIdx.x & 63) == 0) { sc[wib] = c; sv[wib] = valid; }
    __syncthreads();
    if (threadIdx.x == 0) {
        atomicAdd(rsum, sc[0] + sc[1] + sc[2] + sc[3]);
        atomicAdd(nrp,  sv[0] + sv[1] + sv[2] + sv[3]);
        __threadfence();
        unsigned int done = atomicAdd(ticket, 1u);
        if (done == gridDim.x - 1) {
            // all blocks' atomics are visible (device-scope); read via atomics
            float sqt = atomicAdd(sq_total, 0.0f);
            float rs  = atomicAdd(rsum, 0.0f);
            unsigned int n = atomicAdd(nrp, 0u);
            float loss = 0.5f * sqt / 2.0e7f;        // NB*NT = 2e7
            if (n > 0) loss += RANK_W * rs / (float)n;
            out[0] = loss;
        }
    }
}

extern "C" void kernel_launch(void* const* d_in, const int* in_sizes, int n_in,
                              void* d_out, int out_size, void* d_ws, size_t ws_size,
                              hipStream_t stream) {
    const float* scores = (const float*)d_in[0];
    const int*   pb     = (const int*)d_in[1];
    const int*   pt     = (const int*)d_in[2];
    float*       out    = (float*)d_out;

    char* ws = (char*)d_ws;
    unsigned int* mask     = (unsigned int*)ws;
    float*        sq_total = (float*)(ws + 2560000);
    float*        rsum     = (float*)(ws + 2560004);
    unsigned int* nrp      = (unsigned int*)(ws + 2560008);
    unsigned int* ticket   = (unsigned int*)(ws + 2560012);
    float*        top5     = (float*)(ws + 2560016);
    int*          numneg   = (int*)(ws + 2960016);

    zero_ws_kernel<<<(ZERO_U4 + 255) / 256, 256, 0, stream>>>((uint4*)ws);
    scatter_labels_kernel<<<(P_PAIRS + 255) / 256, 256, 0, stream>>>(pb, pt, mask);
    row_kernel<<<NB / 16, 256, 0, stream>>>(scores, mask, sq_total, top5, numneg);
    pair_finalize_kernel<<<(P_PAIRS + 255) / 256, 256, 0, stream>>>(
        scores, pb, pt, top5, numneg, sq_total, rsum, nrp, ticket, out);
}